// Round 12
// baseline (128.757 us; speedup 1.0000x reference)
//
#include <hip/hip_runtime.h>

// GaussianKernelRegression == flash attention:
//   s[n,m] = (q_n . t_m - 0.5*|t_m|^2) / std_n^2  (q^2 drops in softmax)
//   out = softmax_m(s) @ source_db
// V14 = V13 (32x32x16 full-rate pipeline, 100us k_main) + TWO ANTI-PHASED
// BARRIER GROUPS PER CU. r11 pipe accounting: MFMA 29 + VALU 35 + LDS 31
// ~= 95 ~= 100us measured -> phases still serialize inside the single
// 8-wave barrier group. Fix: 4-wave 256-thr blocks (IDENTICAL per-wave code,
// same 32q amortization -> no r9-style traffic inflation), 2-buf LDS
// 67.6KB -> 2 blocks/CU (135KB < 160KB; VGPR 128 = exactly the 4-wave/SIMD
// cap). Block A's softmax/stage overlaps block B's MFMA/ds_read.
// Grid 512 = 32 qblk x 16 chunks; co-resident bids b,b+256 share the chunk
// (256%16==0) -> same XCD-L2 data. Prefetch depth 1 tile: the end-of-tile
// vmcnt(0) drains loads issued a full tile (~2000cy) earlier -> free.
//  - t_sq folded as K-ext (k=256 f16-hi, k=257 f16-lo), NCC=17.
//  - Softmax in-register, 1 shfl_xor(32) for max + 1 for sum.
//  - P -> 32x32x16 B-frag via 8 packed shfl_xor(32) + select (exact).
//  - Defer-max THR=8; normalized f16 partials; layouts HW-verified (r1).

#define N_Q 4096
#define M_DB 16384
#define D_K 256
#define NCC 17               // k-chunks of 16 (c16 = tsq fold at k=256,257)
#define BQ 128
#define BM 32
#define NCHUNK 16
#define MC (M_DB / NCHUNK)   // 1024
#define NTILE (MC / BM)      // 32
#define LOG2E 1.44269504088896f
#define THR 8.0f
#define TOFF 17408           // T bytes per tile (17 KB)
#define TILE_B 33792         // T 17408 + V 16384

typedef _Float16 f16;
typedef _Float16 f16x2v __attribute__((ext_vector_type(2)));
typedef _Float16 f16x4v __attribute__((ext_vector_type(4)));
typedef _Float16 f16x8 __attribute__((ext_vector_type(8)));
typedef float f32x16 __attribute__((ext_vector_type(16)));
typedef unsigned short u16;
typedef unsigned int u32;
typedef u32 u32x4 __attribute__((ext_vector_type(4)));

typedef const __attribute__((address_space(1))) void cg_void;
typedef __attribute__((address_space(3))) void lds_void;

__device__ __forceinline__ void gload16(const void* g, void* s) {
  __builtin_amdgcn_global_load_lds((cg_void*)g, (lds_void*)s, 16, 0, 0);
}

// ---------- prep: Q B-frag blobs (32x32x16): slot=c*64+l, lane l elem e ->
// Q[qt*32 + (l&31)][c*16 + (l>>5)*8 + e]; k=256,257 -> 1.0 (tsq fold), else 0
__global__ void k_prep_q(const float* __restrict__ q, char* __restrict__ qpk) {
  int qt = blockIdx.x;   // 128 tiles of 32 q
  int t = threadIdx.x;
  for (int i = 0; i < 5; i++) {
    int slot = t + 256 * i;
    if (slot >= NCC * 64) break;
    int c = slot >> 6, l = slot & 63;
    int row = qt * 32 + (l & 31);
    int k0 = c * 16 + (l >> 5) * 8;
    f16x8 o;
    for (int e = 0; e < 8; e++) {
      int k = k0 + e;
      float v = (k < D_K) ? q[(size_t)row * D_K + k] : ((k <= D_K + 1) ? 1.0f : 0.0f);
      o[e] = (f16)v;
    }
    *(f16x8*)(qpk + (size_t)qt * TOFF + slot * 16) = o;
  }
}

// ---------- prep: T A-frag blobs (32x32x16) + exact f16hi/lo tsq fold ----------
__global__ void k_prep_t(const float* __restrict__ tdb, char* __restrict__ pkTV) {
  int ti = blockIdx.x;   // 512 tiles of 32 m
  int t = threadIdx.x;
  __shared__ float tsq[32];
  {
    int r = t >> 3, seg = t & 7;
    const float* p = tdb + (size_t)(ti * 32 + r) * D_K + seg * 32;
    float s = 0.f;
    for (int j = 0; j < 32; j++) { float x = p[j]; s += x * x; }
    s += __shfl_xor(s, 1); s += __shfl_xor(s, 2); s += __shfl_xor(s, 4);
    if (seg == 0) tsq[r] = 0.5f * s;
  }
  __syncthreads();
  for (int i = 0; i < 5; i++) {
    int slot = t + 256 * i;
    if (slot >= NCC * 64) break;
    int c = slot >> 6, l = slot & 63;
    int row = l & 31;
    int k0 = c * 16 + (l >> 5) * 8;
    float ts = tsq[row];
    f16 th = (f16)(-ts);
    f16x8 o;
    for (int e = 0; e < 8; e++) {
      int k = k0 + e;
      f16 h;
      if (k < D_K)            h = (f16)tdb[(size_t)(ti * 32 + row) * D_K + k];
      else if (k == D_K)      h = th;
      else if (k == D_K + 1)  h = (f16)(-ts - (float)th);   // lo residual
      else                    h = (f16)0.f;
      o[e] = h;
    }
    *(f16x8*)(pkTV + (size_t)ti * TILE_B + slot * 16) = o;
  }
}

// ---------- prep: V^T A-frag blobs (32x32x16): sub = kh*8+db, lane l elem e ->
// V[ti*32 + kh*16 + (l>>5)*8 + e][db*32 + (l&31)]
__global__ void k_prep_v(const float* __restrict__ src, char* __restrict__ pkTV) {
  int ti = blockIdx.x;   // 512
  int t = threadIdx.x;
  for (int i = 0; i < 4; i++) {
    int slot = t + 256 * i;   // 1024
    int sub = slot >> 6, l = slot & 63;
    int kh = sub >> 3, db = sub & 7;
    int m = ti * 32 + kh * 16 + (l >> 5) * 8;
    int d = db * 32 + (l & 31);
    f16x8 o;
    for (int e = 0; e < 8; e++) o[e] = (f16)src[(size_t)(m + e) * D_K + d];
    *(f16x8*)(pkTV + (size_t)ti * TILE_B + TOFF + slot * 16) = o;
  }
}

// ---------- main flash kernel: 4 waves, 67.6KB LDS, 2 blocks/CU ----------
__launch_bounds__(256, 2)
__global__ void k_main(const char* __restrict__ qpk, const char* __restrict__ pkTV,
                       const float* __restrict__ stdv,
                       u16* __restrict__ pO, float* __restrict__ pm, float* __restrict__ pl)
{
  __shared__ __align__(16) char su[2 * TILE_B];   // 67.6 KB, 2-buf

  const int bid = blockIdx.x, chunk = bid & 15, qblk = bid >> 4;
  const int tid = threadIdx.x;
  const int w = tid >> 6, l = tid & 63;
  const int lq = l & 31, hi = l >> 5;

  const int qrow = qblk * BQ + w * 32 + lq;
  const float sd = stdv[qrow];
  const float is2l = LOG2E / (sd * sd);

  // Q B-frags in registers (68 VGPRs)
  f16x8 qf[NCC];
  {
    const char* qb = qpk + (size_t)(qblk * 4 + w) * TOFF + l * 16;
#pragma unroll
    for (int c = 0; c < NCC; c++) qf[c] = *(const f16x8*)(qb + c * 1024);
  }

  f32x16 acc[8];   // O^T: d = db*32 + (r&3)+8*(r>>2)+4*hi, col q = l&31
#pragma unroll
  for (int db = 0; db < 8; db++)
#pragma unroll
    for (int j = 0; j < 16; j++) acc[db][j] = 0.f;
  float mrun = -3.0e38f, lrun = 0.f;

  const size_t tbase = (size_t)chunk * NTILE;

  auto stage = [&](int t, int buf) {   // 9 VM ops/wave: 8 full 4KB + 1KB tail
    const char* g = pkTV + (tbase + t) * TILE_B;
    char* sb = &su[0] + buf * TILE_B;
#pragma unroll
    for (int i = 0; i < 8; i++)
      gload16(g + i * 4096 + tid * 16, sb + i * 4096 + w * 1024);
    if (l < 16) gload16(g + 32768 + w * 256 + l * 16, sb + 32768 + w * 256);
  };

  // prologue: stage tile 0, full drain (one-time)
  stage(0, 0);
  asm volatile("s_waitcnt vmcnt(0)" ::: "memory");
  __builtin_amdgcn_s_barrier();

  for (int t = 0; t < NTILE; ++t) {
    const int cur = t & 1;
    if (t + 1 < NTILE) stage(t + 1, cur ^ 1);

    // ---- QK^T: A=T (full 32m), B=Q regs -> D[m][q]; 2 chains (even/odd c) ----
    f32x16 sA, sB;
#pragma unroll
    for (int j = 0; j < 16; j++) { sA[j] = 0.f; sB[j] = 0.f; }
    const char* tb = &su[0] + cur * TILE_B + l * 16;
    __builtin_amdgcn_s_setprio(1);
#pragma unroll
    for (int c = 0; c < NCC - 1; c += 2) {
      sA = __builtin_amdgcn_mfma_f32_32x32x16_f16(*(const f16x8*)(tb + c * 1024), qf[c], sA, 0, 0, 0);
      sB = __builtin_amdgcn_mfma_f32_32x32x16_f16(*(const f16x8*)(tb + (c + 1) * 1024), qf[c + 1], sB, 0, 0, 0);
    }
    sA = __builtin_amdgcn_mfma_f32_32x32x16_f16(*(const f16x8*)(tb + 16 * 1024), qf[16], sA, 0, 0, 0);
    __builtin_amdgcn_s_setprio(0);

    float l2[16];
#pragma unroll
    for (int j = 0; j < 16; j++) l2[j] = (sA[j] + sB[j]) * is2l;   // base-2 logits

    // max over 16 regs (tree) + 1 cross-lane
    float a0 = fmaxf(l2[0], l2[1]),  a1 = fmaxf(l2[2], l2[3]);
    float a2 = fmaxf(l2[4], l2[5]),  a3 = fmaxf(l2[6], l2[7]);
    float a4 = fmaxf(l2[8], l2[9]),  a5 = fmaxf(l2[10], l2[11]);
    float a6 = fmaxf(l2[12], l2[13]), a7 = fmaxf(l2[14], l2[15]);
    float px = fmaxf(fmaxf(fmaxf(a0, a1), fmaxf(a2, a3)),
                     fmaxf(fmaxf(a4, a5), fmaxf(a6, a7)));
    px = fmaxf(px, __shfl_xor(px, 32));

    // T13 defer-max: rescale only when max grew by > THR (log2) -> ~never
    if (__any(px > mrun + THR)) {
      const float mnew = fmaxf(mrun, px);
      const float cl = exp2f(mrun - mnew);
      mrun = mnew; lrun *= cl;
#pragma unroll
      for (int db = 0; db < 8; db++)
#pragma unroll
        for (int j = 0; j < 16; j++) acc[db][j] *= cl;
    }
    float pr[16];
#pragma unroll
    for (int j = 0; j < 16; j++) pr[j] = exp2f(l2[j] - mrun);
    float s0 = (pr[0] + pr[1]) + (pr[2] + pr[3]);
    float s1 = (pr[4] + pr[5]) + (pr[6] + pr[7]);
    float s2 = (pr[8] + pr[9]) + (pr[10] + pr[11]);
    float s3 = (pr[12] + pr[13]) + (pr[14] + pr[15]);
    float ls = (s0 + s1) + (s2 + s3);
    ls += __shfl_xor(ls, 32);
    lrun += ls;

    // ---- P -> 32x32x16 B-frags (exact redistribution via 8 packed xor-32) ----
    u32 pk[8], xk[8];
#pragma unroll
    for (int j = 0; j < 8; j++) {
      f16x2v v; v[0] = (f16)pr[2 * j]; v[1] = (f16)pr[2 * j + 1];
      pk[j] = __builtin_bit_cast(u32, v);
    }
#pragma unroll
    for (int j = 0; j < 8; j++) xk[j] = (u32)__shfl_xor((int)pk[j], 32);
    const bool h = (hi != 0);
    u32x4 w0 = { h ? xk[2] : pk[0], h ? xk[3] : pk[1],
                 h ? pk[2] : xk[0], h ? pk[3] : xk[1] };
    u32x4 w1 = { h ? xk[6] : pk[4], h ? xk[7] : pk[5],
                 h ? pk[6] : xk[4], h ? pk[7] : xk[5] };
    f16x8 B0 = __builtin_bit_cast(f16x8, w0);   // k = m 0..15
    f16x8 B1 = __builtin_bit_cast(f16x8, w1);   // k = m 16..31

    // ---- PV: acc[db] += V^T_frag(kh,db) * B(kh), full-rate 32x32x16 ----
    const char* vb = &su[0] + cur * TILE_B + TOFF + l * 16;
    __builtin_amdgcn_s_setprio(1);
#pragma unroll
    for (int db = 0; db < 8; db++)
      acc[db] = __builtin_amdgcn_mfma_f32_32x32x16_f16(*(const f16x8*)(vb + db * 1024), B0, acc[db], 0, 0, 0);
#pragma unroll
    for (int db = 0; db < 8; db++)
      acc[db] = __builtin_amdgcn_mfma_f32_32x32x16_f16(*(const f16x8*)(vb + 8192 + db * 1024), B1, acc[db], 0, 0, 0);
    __builtin_amdgcn_s_setprio(0);

    // ---- end-of-tile: drain the stage issued at tile start (free), barrier ----
    if (t < NTILE - 1) {
      asm volatile("s_waitcnt vmcnt(0)" ::: "memory");
      __builtin_amdgcn_s_barrier();
    }
  }

  // ---- epilogue: normalize (O = acc/l), store own-chunk partials (f16) ----
  const float inv = 1.0f / lrun;
#pragma unroll
  for (int db = 0; db < 8; db++) {
#pragma unroll
    for (int g = 0; g < 4; g++) {
      f16x4v o4;
#pragma unroll
      for (int r4 = 0; r4 < 4; r4++) o4[r4] = (f16)(acc[db][g * 4 + r4] * inv);
      const int d = db * 32 + g * 8 + hi * 4;
      *(f16x4v*)(pO + ((size_t)chunk * N_Q + qrow) * D_K + d) = o4;
    }
  }
  if (hi == 0) {
    pm[(size_t)chunk * N_Q + qrow] = mrun;
    pl[(size_t)chunk * N_Q + qrow] = lrun;
  }
}

// ---------- combine chunk partials (normalized O-hat convention) ----------
__global__ void k_combine(const u16* __restrict__ pO, const float* __restrict__ pm,
                          const float* __restrict__ pl, float* __restrict__ out)
{
  int n = blockIdx.x, d = threadIdx.x;
  float M = -3.0e38f;
#pragma unroll
  for (int c = 0; c < NCHUNK; c++) M = fmaxf(M, pm[(size_t)c * N_Q + n]);
  float den = 0.f, num = 0.f;
#pragma unroll
  for (int c = 0; c < NCHUNK; c++) {
    float wl = exp2f(pm[(size_t)c * N_Q + n] - M) * pl[(size_t)c * N_Q + n];
    den += wl;
    float v = (float)(*(const f16*)(pO + ((size_t)c * N_Q + n) * D_K + d));
    num += wl * v;
  }
  out[(size_t)n * D_K + d] = num / den;
}

extern "C" void kernel_launch(void* const* d_in, const int* in_sizes, int n_in,
                              void* d_out, int out_size, void* d_ws, size_t ws_size,
                              hipStream_t stream)
{
  const float* q    = (const float*)d_in[0];
  const float* stdv = (const float*)d_in[1];
  const float* src  = (const float*)d_in[2];   // source_db (V)
  const float* tdb  = (const float*)d_in[3];   // target_db (T)
  float* out = (float*)d_out;

  char* wsp = (char*)d_ws;
  char* qpk = wsp;        wsp += (size_t)(N_Q / 32) * TOFF;          // 2.2 MB
  char* pkTV = wsp;       wsp += (size_t)(M_DB / 32) * TILE_B;       // 17.3 MB
  u16* pO = (u16*)wsp;    wsp += (size_t)NCHUNK * N_Q * D_K * 2;     // 33.5 MB
  float* pm = (float*)wsp; wsp += (size_t)NCHUNK * N_Q * 4;
  float* pl = (float*)wsp; wsp += (size_t)NCHUNK * N_Q * 4;

  hipLaunchKernelGGL(k_prep_q, dim3(N_Q / 32), dim3(256), 0, stream, q, qpk);
  hipLaunchKernelGGL(k_prep_t, dim3(M_DB / 32), dim3(256), 0, stream, tdb, pkTV);
  hipLaunchKernelGGL(k_prep_v, dim3(M_DB / 32), dim3(256), 0, stream, src, pkTV);
  hipLaunchKernelGGL(k_main,   dim3((N_Q / BQ) * NCHUNK), dim3(256), 0, stream,
                     qpk, pkTV, stdv, pO, pm, pl);
  hipLaunchKernelGGL(k_combine, dim3(N_Q), dim3(256), 0, stream, pO, pm, pl, out);
}

// Round 13
// 117.198 us; speedup vs baseline: 1.0986x; 1.0986x over previous
//
#include <hip/hip_runtime.h>

// GaussianKernelRegression == flash attention:
//   s[n,m] = (q_n . t_m - 0.5*|t_m|^2) / std_n^2  (q^2 drops in softmax)
//   out = softmax_m(s) @ source_db
// V15 = r11/V13 (best: k_main 100us) + 2-TILE BARRIER PERIODS.
// r12 evidence: 2x4w == 1x8w -> barrier-group size irrelevant; binder is
// phase idle (LDS pipe idles while all waves sit in softmax, ~46% LDS floor).
// Registers pin occupancy at 2 waves/SIMD -> de-phase waves WITHIN the block:
//  - 4 rotating buffers; stage tiles {s+2,s+3} at start of period {s,s+1};
//    ONE vmcnt(0)+barrier per period (16 barriers, was 32). Stages write the
//    buffers whose readers finished before the period-start barrier (safe);
//    the end-of-period vmcnt(0) drains loads issued ~2 tiles earlier (free).
//  - Within a period waves drift a full tile: fast wave's QK ds_reads fill
//    the LDS idle under slow wave's softmax. No new registers (r6 lesson).
//  - This creates the wave role-split where setprio(1) pays (T5 regime).
// Aux: prep_t+prep_v fused; k_combine vectorized (f16x8, 8 n/block).
// Per-wave math identical to r11: 32x32x16 QK (2 chains) + exact tsq K-fold,
// in-register softmax, defer-max THR=8, P->B-frag via 8 packed xor-32,
// full-rate 32x32x16 PV, normalized f16 partials.

#define N_Q 4096
#define M_DB 16384
#define D_K 256
#define NCC 17               // k-chunks of 16 (c16 = tsq fold at k=256,257)
#define BQ 256
#define BM 32
#define NCHUNK 16
#define MC (M_DB / NCHUNK)   // 1024
#define NTILE (MC / BM)      // 32 (even)
#define LOG2E 1.44269504088896f
#define THR 8.0f
#define TOFF 17408           // T bytes per tile (17 KB)
#define TILE_B 33792         // T 17408 + V 16384

typedef _Float16 f16;
typedef _Float16 f16x2v __attribute__((ext_vector_type(2)));
typedef _Float16 f16x4v __attribute__((ext_vector_type(4)));
typedef _Float16 f16x8 __attribute__((ext_vector_type(8)));
typedef float f32x4 __attribute__((ext_vector_type(4)));
typedef float f32x16 __attribute__((ext_vector_type(16)));
typedef unsigned short u16;
typedef unsigned int u32;
typedef u32 u32x4 __attribute__((ext_vector_type(4)));

typedef const __attribute__((address_space(1))) void cg_void;
typedef __attribute__((address_space(3))) void lds_void;

__device__ __forceinline__ void gload16(const void* g, void* s) {
  __builtin_amdgcn_global_load_lds((cg_void*)g, (lds_void*)s, 16, 0, 0);
}

// ---------- prep: Q B-frag blobs (32x32x16): slot=c*64+l, lane l elem e ->
// Q[qt*32 + (l&31)][c*16 + (l>>5)*8 + e]; k=256,257 -> 1.0 (tsq fold), else 0
__global__ void k_prep_q(const float* __restrict__ q, char* __restrict__ qpk) {
  int qt = blockIdx.x;   // 128 tiles of 32 q
  int t = threadIdx.x;
  for (int i = 0; i < 5; i++) {
    int slot = t + 256 * i;
    if (slot >= NCC * 64) break;
    int c = slot >> 6, l = slot & 63;
    int row = qt * 32 + (l & 31);
    int k0 = c * 16 + (l >> 5) * 8;
    f16x8 o;
    for (int e = 0; e < 8; e++) {
      int k = k0 + e;
      float v = (k < D_K) ? q[(size_t)row * D_K + k] : ((k <= D_K + 1) ? 1.0f : 0.0f);
      o[e] = (f16)v;
    }
    *(f16x8*)(qpk + (size_t)qt * TOFF + slot * 16) = o;
  }
}

// ---------- prep: fused T (A-frag + exact f16hi/lo tsq fold) and V^T A-frag ----------
__global__ void k_prep_tv(const float* __restrict__ tdb, const float* __restrict__ src,
                          char* __restrict__ pkTV) {
  int ti = blockIdx.x;   // 512 tiles of 32 m
  int t = threadIdx.x;
  __shared__ float tsq[32];
  {
    int r = t >> 3, seg = t & 7;
    const float* p = tdb + (size_t)(ti * 32 + r) * D_K + seg * 32;
    float s = 0.f;
    for (int j = 0; j < 32; j++) { float x = p[j]; s += x * x; }
    s += __shfl_xor(s, 1); s += __shfl_xor(s, 2); s += __shfl_xor(s, 4);
    if (seg == 0) tsq[r] = 0.5f * s;
  }
  __syncthreads();
  // T pack (17 KB)
  for (int i = 0; i < 5; i++) {
    int slot = t + 256 * i;
    if (slot >= NCC * 64) break;
    int c = slot >> 6, l = slot & 63;
    int row = l & 31;
    int k0 = c * 16 + (l >> 5) * 8;
    float ts = tsq[row];
    f16 th = (f16)(-ts);
    f16x8 o;
    for (int e = 0; e < 8; e++) {
      int k = k0 + e;
      f16 h;
      if (k < D_K)            h = (f16)tdb[(size_t)(ti * 32 + row) * D_K + k];
      else if (k == D_K)      h = th;
      else if (k == D_K + 1)  h = (f16)(-ts - (float)th);   // lo residual
      else                    h = (f16)0.f;
      o[e] = h;
    }
    *(f16x8*)(pkTV + (size_t)ti * TILE_B + slot * 16) = o;
  }
  // V pack (16 KB): sub=kh*8+db, lane l elem e -> V[ti*32+kh*16+(l>>5)*8+e][db*32+(l&31)]
  for (int i = 0; i < 4; i++) {
    int slot = t + 256 * i;   // 1024
    int sub = slot >> 6, l = slot & 63;
    int kh = sub >> 3, db = sub & 7;
    int m = ti * 32 + kh * 16 + (l >> 5) * 8;
    int d = db * 32 + (l & 31);
    f16x8 o;
    for (int e = 0; e < 8; e++) o[e] = (f16)src[(size_t)(m + e) * D_K + d];
    *(f16x8*)(pkTV + (size_t)ti * TILE_B + TOFF + slot * 16) = o;
  }
}

// ---------- main flash kernel ----------
__launch_bounds__(512, 2)
__global__ void k_main(const char* __restrict__ qpk, const char* __restrict__ pkTV,
                       const float* __restrict__ stdv,
                       u16* __restrict__ pO, float* __restrict__ pm, float* __restrict__ pl)
{
  __shared__ __align__(16) char su[4 * TILE_B];   // 132 KB, 4-buf rotating

  const int bid = blockIdx.x, chunk = bid & 15, qblk = bid >> 4;
  const int tid = threadIdx.x;
  const int w = tid >> 6, l = tid & 63;
  const int lq = l & 31, hi = l >> 5;

  const int qrow = qblk * BQ + w * 32 + lq;
  const float sd = stdv[qrow];
  const float is2l = LOG2E / (sd * sd);

  // Q B-frags in registers (68 VGPRs)
  f16x8 qf[NCC];
  {
    const char* qb = qpk + (size_t)(qblk * 8 + w) * TOFF + l * 16;
#pragma unroll
    for (int c = 0; c < NCC; c++) qf[c] = *(const f16x8*)(qb + c * 1024);
  }

  f32x16 acc[8];   // O^T: d = db*32 + (r&3)+8*(r>>2)+4*hi, col q = l&31
#pragma unroll
  for (int db = 0; db < 8; db++)
#pragma unroll
    for (int j = 0; j < 16; j++) acc[db][j] = 0.f;
  float mrun = -3.0e38f, lrun = 0.f;

  const size_t tbase = (size_t)chunk * NTILE;

  auto stage = [&](int t, int buf) {   // 5 VM ops/wave: 4 full + 1 masked (1KB tail)
    const char* g = pkTV + (tbase + t) * TILE_B;
    char* sb = &su[0] + buf * TILE_B;
#pragma unroll
    for (int i = 0; i < 4; i++)
      gload16(g + i * 8192 + tid * 16, sb + i * 8192 + w * 1024);
    if (l < 8) gload16(g + 32768 + w * 128 + l * 16, sb + 32768 + w * 128);
  };

  // one full tile: QK -> softmax -> P-pack -> PV (no barrier inside)
  auto body = [&](int t) {
    const int cur = t & 3;
    // ---- QK^T: A=T (full 32m), B=Q regs -> D[m][q]; 2 chains (even/odd c) ----
    f32x16 sA, sB;
#pragma unroll
    for (int j = 0; j < 16; j++) { sA[j] = 0.f; sB[j] = 0.f; }
    const char* tb = &su[0] + cur * TILE_B + l * 16;
    __builtin_amdgcn_s_setprio(1);
#pragma unroll
    for (int c = 0; c < NCC - 1; c += 2) {
      sA = __builtin_amdgcn_mfma_f32_32x32x16_f16(*(const f16x8*)(tb + c * 1024), qf[c], sA, 0, 0, 0);
      sB = __builtin_amdgcn_mfma_f32_32x32x16_f16(*(const f16x8*)(tb + (c + 1) * 1024), qf[c + 1], sB, 0, 0, 0);
    }
    sA = __builtin_amdgcn_mfma_f32_32x32x16_f16(*(const f16x8*)(tb + 16 * 1024), qf[16], sA, 0, 0, 0);
    __builtin_amdgcn_s_setprio(0);

    float l2[16];
#pragma unroll
    for (int j = 0; j < 16; j++) l2[j] = (sA[j] + sB[j]) * is2l;   // base-2 logits

    float a0 = fmaxf(l2[0], l2[1]),  a1 = fmaxf(l2[2], l2[3]);
    float a2 = fmaxf(l2[4], l2[5]),  a3 = fmaxf(l2[6], l2[7]);
    float a4 = fmaxf(l2[8], l2[9]),  a5 = fmaxf(l2[10], l2[11]);
    float a6 = fmaxf(l2[12], l2[13]), a7 = fmaxf(l2[14], l2[15]);
    float px = fmaxf(fmaxf(fmaxf(a0, a1), fmaxf(a2, a3)),
                     fmaxf(fmaxf(a4, a5), fmaxf(a6, a7)));
    px = fmaxf(px, __shfl_xor(px, 32));

    // T13 defer-max: rescale only when max grew by > THR (log2) -> ~never
    if (__any(px > mrun + THR)) {
      const float mnew = fmaxf(mrun, px);
      const float cl = exp2f(mrun - mnew);
      mrun = mnew; lrun *= cl;
#pragma unroll
      for (int db = 0; db < 8; db++)
#pragma unroll
        for (int j = 0; j < 16; j++) acc[db][j] *= cl;
    }
    float pr[16];
#pragma unroll
    for (int j = 0; j < 16; j++) pr[j] = exp2f(l2[j] - mrun);
    float s0 = (pr[0] + pr[1]) + (pr[2] + pr[3]);
    float s1 = (pr[4] + pr[5]) + (pr[6] + pr[7]);
    float s2 = (pr[8] + pr[9]) + (pr[10] + pr[11]);
    float s3 = (pr[12] + pr[13]) + (pr[14] + pr[15]);
    float ls = (s0 + s1) + (s2 + s3);
    ls += __shfl_xor(ls, 32);
    lrun += ls;

    // ---- P -> 32x32x16 B-frags (exact redistribution via 8 packed xor-32) ----
    u32 pk[8], xk[8];
#pragma unroll
    for (int j = 0; j < 8; j++) {
      f16x2v v; v[0] = (f16)pr[2 * j]; v[1] = (f16)pr[2 * j + 1];
      pk[j] = __builtin_bit_cast(u32, v);
    }
#pragma unroll
    for (int j = 0; j < 8; j++) xk[j] = (u32)__shfl_xor((int)pk[j], 32);
    const bool h = (hi != 0);
    u32x4 w0 = { h ? xk[2] : pk[0], h ? xk[3] : pk[1],
                 h ? pk[2] : xk[0], h ? pk[3] : xk[1] };
    u32x4 w1 = { h ? xk[6] : pk[4], h ? xk[7] : pk[5],
                 h ? pk[6] : xk[4], h ? pk[7] : xk[5] };
    f16x8 B0 = __builtin_bit_cast(f16x8, w0);   // k = m 0..15
    f16x8 B1 = __builtin_bit_cast(f16x8, w1);   // k = m 16..31

    // ---- PV: acc[db] += V^T_frag(kh,db) * B(kh), full-rate 32x32x16 ----
    const char* vb = &su[0] + cur * TILE_B + TOFF + l * 16;
    __builtin_amdgcn_s_setprio(1);
#pragma unroll
    for (int db = 0; db < 8; db++)
      acc[db] = __builtin_amdgcn_mfma_f32_32x32x16_f16(*(const f16x8*)(vb + db * 1024), B0, acc[db], 0, 0, 0);
#pragma unroll
    for (int db = 0; db < 8; db++)
      acc[db] = __builtin_amdgcn_mfma_f32_32x32x16_f16(*(const f16x8*)(vb + 8192 + db * 1024), B1, acc[db], 0, 0, 0);
    __builtin_amdgcn_s_setprio(0);
  };

  // prologue: stage tiles 0,1; full drain (one-time); periods stage 2 ahead
  stage(0, 0);
  stage(1, 1);
  asm volatile("s_waitcnt vmcnt(0)" ::: "memory");
  __builtin_amdgcn_s_barrier();

  for (int s = 0; s < NTILE; s += 2) {
    // stage next period's pair into the buffers freed before the last barrier
    if (s + 2 < NTILE) stage(s + 2, (s + 2) & 3);
    if (s + 3 < NTILE) stage(s + 3, (s + 3) & 3);
    body(s);
    body(s + 1);   // waves drift across the pair: reads fill softmax idle
    if (s + 2 < NTILE) {
      asm volatile("s_waitcnt vmcnt(0)" ::: "memory");   // drains ~2-tile-old loads
      __builtin_amdgcn_s_barrier();
    }
  }

  // ---- epilogue: normalize (O = acc/l), store own-chunk partials (f16) ----
  const float inv = 1.0f / lrun;
#pragma unroll
  for (int db = 0; db < 8; db++) {
#pragma unroll
    for (int g = 0; g < 4; g++) {
      f16x4v o4;
#pragma unroll
      for (int r4 = 0; r4 < 4; r4++) o4[r4] = (f16)(acc[db][g * 4 + r4] * inv);
      const int d = db * 32 + g * 8 + hi * 4;
      *(f16x4v*)(pO + ((size_t)chunk * N_Q + qrow) * D_K + d) = o4;
    }
  }
  if (hi == 0) {
    pm[(size_t)chunk * N_Q + qrow] = mrun;
    pl[(size_t)chunk * N_Q + qrow] = lrun;
  }
}

// ---------- combine chunk partials (vectorized: 8 n/block, f16x8 loads) ----------
__global__ void k_combine(const u16* __restrict__ pO, const float* __restrict__ pm,
                          const float* __restrict__ pl, float* __restrict__ out)
{
  const int t = threadIdx.x;
  const int n = blockIdx.x * 8 + (t >> 5);   // 8 rows per 256-thr block
  const int j = t & 31;                      // lane owns d = j*8 .. j*8+7
  float M = -3.0e38f;
#pragma unroll
  for (int c = 0; c < NCHUNK; c++) M = fmaxf(M, pm[(size_t)c * N_Q + n]);
  float den = 0.f;
  float o[8];
#pragma unroll
  for (int e = 0; e < 8; e++) o[e] = 0.f;
#pragma unroll
  for (int c = 0; c < NCHUNK; c++) {
    const float wl = exp2f(pm[(size_t)c * N_Q + n] - M) * pl[(size_t)c * N_Q + n];
    den += wl;
    const f16x8 v = *(const f16x8*)(pO + ((size_t)c * N_Q + n) * D_K + j * 8);
#pragma unroll
    for (int e = 0; e < 8; e++) o[e] += wl * (float)v[e];
  }
  const float inv = 1.0f / den;
  f32x4 w0, w1;
#pragma unroll
  for (int e = 0; e < 4; e++) { w0[e] = o[e] * inv; w1[e] = o[4 + e] * inv; }
  float* dst = out + (size_t)n * D_K + j * 8;
  *(f32x4*)dst = w0;
  *(f32x4*)(dst + 4) = w1;
}

extern "C" void kernel_launch(void* const* d_in, const int* in_sizes, int n_in,
                              void* d_out, int out_size, void* d_ws, size_t ws_size,
                              hipStream_t stream)
{
  const float* q    = (const float*)d_in[0];
  const float* stdv = (const float*)d_in[1];
  const float* src  = (const float*)d_in[2];   // source_db (V)
  const float* tdb  = (const float*)d_in[3];   // target_db (T)
  float* out = (float*)d_out;

  char* wsp = (char*)d_ws;
  char* qpk = wsp;        wsp += (size_t)(N_Q / 32) * TOFF;          // 2.2 MB
  char* pkTV = wsp;       wsp += (size_t)(M_DB / 32) * TILE_B;       // 17.3 MB
  u16* pO = (u16*)wsp;    wsp += (size_t)NCHUNK * N_Q * D_K * 2;     // 33.5 MB
  float* pm = (float*)wsp; wsp += (size_t)NCHUNK * N_Q * 4;
  float* pl = (float*)wsp; wsp += (size_t)NCHUNK * N_Q * 4;

  hipLaunchKernelGGL(k_prep_q,  dim3(N_Q / 32), dim3(256), 0, stream, q, qpk);
  hipLaunchKernelGGL(k_prep_tv, dim3(M_DB / 32), dim3(256), 0, stream, tdb, src, pkTV);
  hipLaunchKernelGGL(k_main,    dim3((N_Q / BQ) * NCHUNK), dim3(512), 0, stream,
                     qpk, pkTV, stdv, pO, pm, pl);
  hipLaunchKernelGGL(k_combine, dim3(N_Q / 8), dim3(256), 0, stream, pO, pm, pl, out);
}